// Round 11
// baseline (282.560 us; speedup 1.0000x reference)
//
#include <hip/hip_runtime.h>

#define BB 4
#define NN 256
#define DD 256
#define HH 256
#define NEGV -1.0e9f

typedef _Float16 half8 __attribute__((ext_vector_type(8)));
typedef __fp16   fp16x2 __attribute__((ext_vector_type(2)));
typedef float floatx4 __attribute__((ext_vector_type(4)));

// ---------------- prep: Wc/Wd -> f16 fragment-contiguous; Xt = X^T; S/T -------
// Wst layout: [ks 0..15][hgrp 0..15][q 0..3][cc 0..15][e 0..7] halves.
// Fragment (ks,hgrp,q) holds B16[k=ks*32+q*8+e][h=hgrp*16+cc]; k=2*d+t
// (t=0: Wc[d][h], t=1: Wd[d][h]).  Per-kstep 16 KB block == LDS image (DMA-able).
// Xt layout: [b][d][j] fp32 (A-gen loads are j-contiguous/coalesced).
__global__ __launch_bounds__(256) void prep_kernel(const float* __restrict__ X,
                                                   const float* __restrict__ W1,
                                                   float* __restrict__ S,
                                                   float* __restrict__ T,
                                                   _Float16* __restrict__ Wst,
                                                   float* __restrict__ Xt) {
  const int g = blockIdx.x;    // d = 0..255
  const int h = threadIdx.x;   // 0..255

  {
    const float wcv = W1[(size_t)(2 * DD + g) * HH + h];
    const float wdv = W1[(size_t)(3 * DD + g) * HH + h];
    const int ks = g >> 4;
    const int dd = g & 15;
    const int q  = dd >> 2;
    const int e  = (dd & 3) * 2;
    const int hgrp = h >> 4;
    const int ccw  = h & 15;
    _Float16* p = Wst + ((size_t)((ks * 16 + hgrp) * 4 + q) * 16 + ccw) * 8 + e;
    p[0] = (_Float16)wcv;
    p[1] = (_Float16)wdv;
  }

  const int row0 = g * 4;
  __shared__ float xr[4][DD];
#pragma unroll
  for (int r = 0; r < 4; ++r) xr[r][h] = X[(size_t)(row0 + r) * DD + h];
  __syncthreads();

  {
    const int bb = row0 >> 8;
    const int j0 = row0 & 255;
    float* xt = Xt + (size_t)bb * DD * NN + (size_t)h * NN + j0;
    xt[0] = xr[0][h]; xt[1] = xr[1][h]; xt[2] = xr[2][h]; xt[3] = xr[3][h];
  }

  const float* __restrict__ Wa = W1;
  const float* __restrict__ Wb = W1 + (size_t)DD * HH;
  float sa0 = 0.f, sa1 = 0.f, sa2 = 0.f, sa3 = 0.f;
  float sb0 = 0.f, sb1 = 0.f, sb2 = 0.f, sb3 = 0.f;
  for (int d = 0; d < DD; ++d) {
    const float wa = Wa[(size_t)d * HH + h];
    const float wb = Wb[(size_t)d * HH + h];
    sa0 = fmaf(xr[0][d], wa, sa0);  sb0 = fmaf(xr[0][d], wb, sb0);
    sa1 = fmaf(xr[1][d], wa, sa1);  sb1 = fmaf(xr[1][d], wb, sb1);
    sa2 = fmaf(xr[2][d], wa, sa2);  sb2 = fmaf(xr[2][d], wb, sb2);
    sa3 = fmaf(xr[3][d], wa, sa3);  sb3 = fmaf(xr[3][d], wb, sb3);
  }
  S[(size_t)(row0 + 0) * HH + h] = sa0;  T[(size_t)(row0 + 0) * HH + h] = sb0;
  S[(size_t)(row0 + 1) * HH + h] = sa1;  T[(size_t)(row0 + 1) * HH + h] = sb1;
  S[(size_t)(row0 + 2) * HH + h] = sa2;  T[(size_t)(row0 + 2) * HH + h] = sb2;
  S[(size_t)(row0 + 3) * HH + h] = sa3;  T[(size_t)(row0 + 3) * HH + h] = sb3;
}

__device__ __forceinline__ half8 make_afrag(float ia, float ib, float ic, float id,
                                            float ja, float jb, float jc, float jd) {
  fp16x2 p0 = __builtin_amdgcn_cvt_pkrtz(__builtin_fabsf(ia - ja), ia * ja);
  fp16x2 p1 = __builtin_amdgcn_cvt_pkrtz(__builtin_fabsf(ib - jb), ib * jb);
  fp16x2 p2 = __builtin_amdgcn_cvt_pkrtz(__builtin_fabsf(ic - jc), ic * jc);
  fp16x2 p3 = __builtin_amdgcn_cvt_pkrtz(__builtin_fabsf(id - jd), id * jd);
  uint4 u;
  u.x = __builtin_bit_cast(unsigned int, p0);
  u.y = __builtin_bit_cast(unsigned int, p1);
  u.z = __builtin_bit_cast(unsigned int, p2);
  u.w = __builtin_bit_cast(unsigned int, p3);
  return __builtin_bit_cast(half8, u);
}

// async global->LDS, 16 B per lane (gfx950; dst = wave-uniform base + lane*16)
__device__ __forceinline__ void ld_lds16(const char* g, char* l) {
  __builtin_amdgcn_global_load_lds(
      (const __attribute__((address_space(1))) unsigned int*)g,
      (__attribute__((address_space(3))) unsigned int*)l, 16, 0, 0);
}

#define MFMA16(af, bf, acc) acc = __builtin_amdgcn_mfma_f32_16x16x32_f16(af, bf, acc, 0, 0, 0)

// ---------------- score: one block per (b,i) x 128-j half ----------------------
// 2048 blocks x 256 thr = 4 waves (wj=wid&1: 64 j, hg=wid>>1: 128 h).
// Wave tile 4j x 8h = 32 MFMA per (4 A + 8 B) b128 reads — 2x the MFMA:LDS-read
// ratio of R10 (which was LDS-issue-bound: 1536 read-cyc vs 1241 MFMA-cyc/CU).
// B staged by global_load_lds width=16 (no VALU, no ds_write, conflict-free).
__global__ __launch_bounds__(256) void score_mfma(
    const float* __restrict__ X,  const float* __restrict__ b1,
    const float* __restrict__ W2, const float* __restrict__ b2,
    const float* __restrict__ S,  const float* __restrict__ T,
    const _Float16* __restrict__ Wst, const float* __restrict__ Xt,
    float* __restrict__ Sc) {

  const int blk   = blockIdx.x;
  const int bi    = blk >> 1;       // b*256 + i
  const int jbase = (blk & 1) * 128;
  const int b     = bi >> 8;
  const int i     = bi & 255;
  const int t     = threadIdx.x;    // 0..255
  const int lane  = t & 63;
  const int wid   = t >> 6;         // 0..3
  const int wj    = wid & 1;
  const int hg    = wid >> 1;       // 0..1
  const int q     = lane >> 4;
  const int cc    = lane & 15;

  __shared__ __align__(16) float    xi_s[DD];
  __shared__ float pre_s[HH];
  __shared__ float w2_s[HH];
  __shared__ __align__(16) _Float16 As[2][4096];   // 8 KB per buf
  __shared__ __align__(16) _Float16 Bs[2][8192];   // 16 KB per buf
  __shared__ float sc_s[2][128];

  xi_s[t]  = X[(size_t)bi * DD + t];
  pre_s[t] = S[(size_t)bi * HH + t] + b1[t];
  w2_s[t]  = W2[t];
  __syncthreads();                  // xi_s needed by A-gen

  const float* __restrict__ Tb = T + (size_t)b * NN * HH;

  // A-gen role: thread t -> (qh = t>>7, jl = t&127), handles qa in {qh, qh+2}.
  const int qh = t >> 7;
  const int jl = t & 127;
  const float* __restrict__ xsrc = Xt + (size_t)b * DD * NN + jbase + jl;
  const int awo1 = ((jl >> 4) * 4 + qh) * 128 + (jl & 15) * 8;        // halves
  const int awo2 = ((jl >> 4) * 4 + qh + 2) * 128 + (jl & 15) * 8;

  // B async staging: wave wid covers bytes [wid*4096, wid*4096+4096) of 16 KB.
  const char* __restrict__ WstB = (const char*)Wst;   // kstep ks at byte ks*16384
  char* BsB = (char*)&Bs[0][0];
  const int bsub = wid * 4096 + lane * 16;            // per-lane source offset

  // fragment read offsets (halves)
  const int bro = hg * 4096 + lane * 8;   // hh advances +512
  const int aro = wj * 2048 + lane * 8;   // jj advances +512

  floatx4 c00=(floatx4)0.f,c01=(floatx4)0.f,c02=(floatx4)0.f,c03=(floatx4)0.f,
          c04=(floatx4)0.f,c05=(floatx4)0.f,c06=(floatx4)0.f,c07=(floatx4)0.f;
  floatx4 c10=(floatx4)0.f,c11=(floatx4)0.f,c12=(floatx4)0.f,c13=(floatx4)0.f,
          c14=(floatx4)0.f,c15=(floatx4)0.f,c16=(floatx4)0.f,c17=(floatx4)0.f;
  floatx4 c20=(floatx4)0.f,c21=(floatx4)0.f,c22=(floatx4)0.f,c23=(floatx4)0.f,
          c24=(floatx4)0.f,c25=(floatx4)0.f,c26=(floatx4)0.f,c27=(floatx4)0.f;
  floatx4 c30=(floatx4)0.f,c31=(floatx4)0.f,c32=(floatx4)0.f,c33=(floatx4)0.f,
          c34=(floatx4)0.f,c35=(floatx4)0.f,c36=(floatx4)0.f,c37=(floatx4)0.f;

  // ---- prologue: stage kstep 0 into buffer 0 ----
  {
    ld_lds16(WstB + bsub,        BsB + wid * 4096);
    ld_lds16(WstB + bsub + 1024, BsB + wid * 4096 + 1024);
    ld_lds16(WstB + bsub + 2048, BsB + wid * 4096 + 2048);
    ld_lds16(WstB + bsub + 3072, BsB + wid * 4096 + 3072);
    const int d1 = qh * 4, d2 = (qh + 2) * 4;
    const float y0 = xsrc[(size_t)(d1 + 0) * NN], y1 = xsrc[(size_t)(d1 + 1) * NN];
    const float y2 = xsrc[(size_t)(d1 + 2) * NN], y3 = xsrc[(size_t)(d1 + 3) * NN];
    const float y4 = xsrc[(size_t)(d2 + 0) * NN], y5 = xsrc[(size_t)(d2 + 1) * NN];
    const float y6 = xsrc[(size_t)(d2 + 2) * NN], y7 = xsrc[(size_t)(d2 + 3) * NN];
    *(half8*)&As[0][awo1] = make_afrag(xi_s[d1], xi_s[d1+1], xi_s[d1+2], xi_s[d1+3],
                                       y0, y1, y2, y3);
    *(half8*)&As[0][awo2] = make_afrag(xi_s[d2], xi_s[d2+1], xi_s[d2+2], xi_s[d2+3],
                                       y4, y5, y6, y7);
  }
  __syncthreads();

#define MFMA_ROW(J, AOFF) { \
    const half8 af = *(const half8*)&ap[AOFF]; \
    MFMA16(af, bf0, c##J##0); MFMA16(af, bf1, c##J##1); \
    MFMA16(af, bf2, c##J##2); MFMA16(af, bf3, c##J##3); \
    MFMA16(af, bf4, c##J##4); MFMA16(af, bf5, c##J##5); \
    MFMA16(af, bf6, c##J##6); MFMA16(af, bf7, c##J##7); }

#pragma unroll 2
  for (int ks = 0; ks < 16; ++ks) {
    const int cur = ks & 1;
    const int nxt = cur ^ 1;
    float y0, y1, y2, y3, y4, y5, y6, y7;
    if (ks < 15) {
      const char* gB = WstB + (size_t)(ks + 1) * 16384;
      ld_lds16(gB + bsub,        BsB + nxt * 16384 + wid * 4096);
      ld_lds16(gB + bsub + 1024, BsB + nxt * 16384 + wid * 4096 + 1024);
      ld_lds16(gB + bsub + 2048, BsB + nxt * 16384 + wid * 4096 + 2048);
      ld_lds16(gB + bsub + 3072, BsB + nxt * 16384 + wid * 4096 + 3072);
      const int d1 = (ks + 1) * 16 + qh * 4;
      const float* __restrict__ xs1 = xsrc + (size_t)d1 * NN;
      y0 = xs1[0]; y1 = xs1[NN]; y2 = xs1[2 * NN]; y3 = xs1[3 * NN];
      const float* __restrict__ xs2 = xs1 + (size_t)8 * NN;
      y4 = xs2[0]; y5 = xs2[NN]; y6 = xs2[2 * NN]; y7 = xs2[3 * NN];
    }

    // ---- compute kstep ks from buffer cur ----
    {
      const _Float16* __restrict__ ap = &As[cur][0];
      const _Float16* __restrict__ bp = &Bs[cur][0];
      const half8 bf0 = *(const half8*)&bp[bro];
      const half8 bf1 = *(const half8*)&bp[bro + 512];
      const half8 bf2 = *(const half8*)&bp[bro + 1024];
      const half8 bf3 = *(const half8*)&bp[bro + 1536];
      const half8 bf4 = *(const half8*)&bp[bro + 2048];
      const half8 bf5 = *(const half8*)&bp[bro + 2560];
      const half8 bf6 = *(const half8*)&bp[bro + 3072];
      const half8 bf7 = *(const half8*)&bp[bro + 3584];
      MFMA_ROW(0, aro)
      MFMA_ROW(1, aro + 512)
      MFMA_ROW(2, aro + 1024)
      MFMA_ROW(3, aro + 1536)
    }

    if (ks < 15) {
      const int d1 = (ks + 1) * 16 + qh * 4;
      const int d2 = d1 + 8;
      *(half8*)&As[nxt][awo1] = make_afrag(xi_s[d1], xi_s[d1+1], xi_s[d1+2], xi_s[d1+3],
                                           y0, y1, y2, y3);
      *(half8*)&As[nxt][awo2] = make_afrag(xi_s[d2], xi_s[d2+1], xi_s[d2+2], xi_s[d2+3],
                                           y4, y5, y6, y7);
    }
    __syncthreads();
  }

  // ---- epilogue: + S_i + T_j + b1, silu, dot w2 ----
  float p00=0.f,p01=0.f,p02=0.f,p03=0.f;
  float p10=0.f,p11=0.f,p12=0.f,p13=0.f;
  float p20=0.f,p21=0.f,p22=0.f,p23=0.f;
  float p30=0.f,p31=0.f,p32=0.f,p33=0.f;

#define EPI_ONE(A, J, R, P) { \
    const float tv = Tb[(size_t)(jbase + wj * 64 + J * 16 + q * 4 + R) * HH + h]; \
    const float hv = A[R] + pv + tv; \
    const float sv = hv * __frcp_rn(1.f + __expf(-hv)); \
    P = fmaf(sv, w2v, P); }

#define EPI_J(CJ, J) \
    EPI_ONE(CJ, J, 0, p##J##0) EPI_ONE(CJ, J, 1, p##J##1) \
    EPI_ONE(CJ, J, 2, p##J##2) EPI_ONE(CJ, J, 3, p##J##3)

#define EPI_HH(HHn) { \
    const int h = hg * 128 + HHn * 16 + cc; \
    const float w2v = w2_s[h]; \
    const float pv  = pre_s[h]; \
    EPI_J(c0##HHn, 0) EPI_J(c1##HHn, 1) EPI_J(c2##HHn, 2) EPI_J(c3##HHn, 3) }

  EPI_HH(0) EPI_HH(1) EPI_HH(2) EPI_HH(3)
  EPI_HH(4) EPI_HH(5) EPI_HH(6) EPI_HH(7)

#define REDW(P, J, R) { \
    float v = P; \
    v += __shfl_xor(v, 1); v += __shfl_xor(v, 2); \
    v += __shfl_xor(v, 4); v += __shfl_xor(v, 8); \
    if (cc == 0) sc_s[hg][wj * 64 + J * 16 + q * 4 + R] = v; }

  REDW(p00, 0, 0) REDW(p01, 0, 1) REDW(p02, 0, 2) REDW(p03, 0, 3)
  REDW(p10, 1, 0) REDW(p11, 1, 1) REDW(p12, 1, 2) REDW(p13, 1, 3)
  REDW(p20, 2, 0) REDW(p21, 2, 1) REDW(p22, 2, 2) REDW(p23, 2, 3)
  REDW(p30, 3, 0) REDW(p31, 3, 1) REDW(p32, 3, 2) REDW(p33, 3, 3)
  __syncthreads();

  if (t < 128) {
    float s = sc_s[0][t] + sc_s[1][t] + b2[0];
    const int jg = jbase + t;
    if (jg == i) s = NEGV;
    Sc[(size_t)bi * NN + jg] = s;
  }
}

// ---------------- softmax over j, one block per (b,i) --------------------------
__global__ __launch_bounds__(256) void softmax_kernel(const float* __restrict__ Sc,
                                                      float* __restrict__ out) {
  const int bi = blockIdx.x;
  const int t  = threadIdx.x;
  __shared__ float red[NN];
  const float s = Sc[(size_t)bi * NN + t];
  red[t] = s;
  __syncthreads();
  for (int k = 128; k > 0; k >>= 1) {
    if (t < k) red[t] = fmaxf(red[t], red[t + k]);
    __syncthreads();
  }
  const float m = red[0];
  __syncthreads();
  const float e = __expf(s - m);
  red[t] = e;
  __syncthreads();
  for (int k = 128; k > 0; k >>= 1) {
    if (t < k) red[t] += red[t + k];
    __syncthreads();
  }
  out[(size_t)bi * NN + t] = e / red[0];
}

extern "C" void kernel_launch(void* const* d_in, const int* in_sizes, int n_in,
                              void* d_out, int out_size, void* d_ws, size_t ws_size,
                              hipStream_t stream) {
  const float* X  = (const float*)d_in[0];
  const float* W1 = (const float*)d_in[1];
  const float* b1 = (const float*)d_in[2];
  const float* W2 = (const float*)d_in[3];
  const float* b2 = (const float*)d_in[4];
  float* out = (float*)d_out;

  float*     Sws = (float*)d_ws;                             // 1 MB
  float*     Tws = Sws + (size_t)BB * NN * HH;               // 1 MB
  _Float16*  Wst = (_Float16*)(Tws + (size_t)BB * NN * HH);  // 256 KB
  float*     Xtw = (float*)(Wst + (size_t)16 * HH * 32);     // 1 MB
  float*     Scw = Xtw + (size_t)BB * DD * NN;               // 1 MB

  prep_kernel<<<256, 256, 0, stream>>>(X, W1, Sws, Tws, Wst, Xtw);
  score_mfma<<<BB * NN * 2, 256, 0, stream>>>(X, b1, W2, b2, Sws, Tws, Wst, Xtw, Scw);
  softmax_kernel<<<BB * NN, 256, 0, stream>>>(Scw, out);
}

// Round 12
// 240.387 us; speedup vs baseline: 1.1754x; 1.1754x over previous
//
#include <hip/hip_runtime.h>

#define BB 4
#define NN 256
#define DD 256
#define HH 256
#define NEGV -1.0e9f

typedef _Float16 half8 __attribute__((ext_vector_type(8)));
typedef __fp16   fp16x2 __attribute__((ext_vector_type(2)));
typedef float floatx4 __attribute__((ext_vector_type(4)));

// ---------------- prep: Wc/Wd -> f16 fragment-contiguous; Xt = X^T; S/T -------
// Wst layout: [ks 0..15][hgrp 0..15][q 0..3][cc 0..15][e 0..7] halves.
// Fragment (ks,hgrp,q) holds B16[k=ks*32+q*8+e][h=hgrp*16+cc]; k=2*d+t
// (t=0: Wc[d][h], t=1: Wd[d][h]).  Per-kstep 16 KB block == LDS image (DMA-able).
// Xt layout: [b][d][j] fp32 (A-gen loads are j-contiguous/coalesced).
__global__ __launch_bounds__(256) void prep_kernel(const float* __restrict__ X,
                                                   const float* __restrict__ W1,
                                                   float* __restrict__ S,
                                                   float* __restrict__ T,
                                                   _Float16* __restrict__ Wst,
                                                   float* __restrict__ Xt) {
  const int g = blockIdx.x;    // d = 0..255
  const int h = threadIdx.x;   // 0..255

  {
    const float wcv = W1[(size_t)(2 * DD + g) * HH + h];
    const float wdv = W1[(size_t)(3 * DD + g) * HH + h];
    const int ks = g >> 4;
    const int dd = g & 15;
    const int q  = dd >> 2;
    const int e  = (dd & 3) * 2;
    const int hgrp = h >> 4;
    const int ccw  = h & 15;
    _Float16* p = Wst + ((size_t)((ks * 16 + hgrp) * 4 + q) * 16 + ccw) * 8 + e;
    p[0] = (_Float16)wcv;
    p[1] = (_Float16)wdv;
  }

  const int row0 = g * 4;
  __shared__ float xr[4][DD];
#pragma unroll
  for (int r = 0; r < 4; ++r) xr[r][h] = X[(size_t)(row0 + r) * DD + h];
  __syncthreads();

  {
    const int bb = row0 >> 8;
    const int j0 = row0 & 255;
    float* xt = Xt + (size_t)bb * DD * NN + (size_t)h * NN + j0;
    xt[0] = xr[0][h]; xt[1] = xr[1][h]; xt[2] = xr[2][h]; xt[3] = xr[3][h];
  }

  const float* __restrict__ Wa = W1;
  const float* __restrict__ Wb = W1 + (size_t)DD * HH;
  float sa0 = 0.f, sa1 = 0.f, sa2 = 0.f, sa3 = 0.f;
  float sb0 = 0.f, sb1 = 0.f, sb2 = 0.f, sb3 = 0.f;
  for (int d = 0; d < DD; ++d) {
    const float wa = Wa[(size_t)d * HH + h];
    const float wb = Wb[(size_t)d * HH + h];
    sa0 = fmaf(xr[0][d], wa, sa0);  sb0 = fmaf(xr[0][d], wb, sb0);
    sa1 = fmaf(xr[1][d], wa, sa1);  sb1 = fmaf(xr[1][d], wb, sb1);
    sa2 = fmaf(xr[2][d], wa, sa2);  sb2 = fmaf(xr[2][d], wb, sb2);
    sa3 = fmaf(xr[3][d], wa, sa3);  sb3 = fmaf(xr[3][d], wb, sb3);
  }
  S[(size_t)(row0 + 0) * HH + h] = sa0;  T[(size_t)(row0 + 0) * HH + h] = sb0;
  S[(size_t)(row0 + 1) * HH + h] = sa1;  T[(size_t)(row0 + 1) * HH + h] = sb1;
  S[(size_t)(row0 + 2) * HH + h] = sa2;  T[(size_t)(row0 + 2) * HH + h] = sb2;
  S[(size_t)(row0 + 3) * HH + h] = sa3;  T[(size_t)(row0 + 3) * HH + h] = sb3;
}

__device__ __forceinline__ half8 make_afrag(float ia, float ib, float ic, float id,
                                            float ja, float jb, float jc, float jd) {
  fp16x2 p0 = __builtin_amdgcn_cvt_pkrtz(__builtin_fabsf(ia - ja), ia * ja);
  fp16x2 p1 = __builtin_amdgcn_cvt_pkrtz(__builtin_fabsf(ib - jb), ib * jb);
  fp16x2 p2 = __builtin_amdgcn_cvt_pkrtz(__builtin_fabsf(ic - jc), ic * jc);
  fp16x2 p3 = __builtin_amdgcn_cvt_pkrtz(__builtin_fabsf(id - jd), id * jd);
  uint4 u;
  u.x = __builtin_bit_cast(unsigned int, p0);
  u.y = __builtin_bit_cast(unsigned int, p1);
  u.z = __builtin_bit_cast(unsigned int, p2);
  u.w = __builtin_bit_cast(unsigned int, p3);
  return __builtin_bit_cast(half8, u);
}

// async global->LDS, 16 B per lane; LDS dst is WAVE-UNIFORM base (+lane*16 implicit)
__device__ __forceinline__ void ld_lds16(const char* g, char* l) {
  __builtin_amdgcn_global_load_lds(
      (const __attribute__((address_space(1))) unsigned int*)g,
      (__attribute__((address_space(3))) unsigned int*)l, 16, 0, 0);
}

#define MFMA16(af, bf, acc) acc = __builtin_amdgcn_mfma_f32_16x16x32_f16(af, bf, acc, 0, 0, 0)

// ---------------- score: one block per (b,i) x 128-j half ----------------------
// R10 shape (512 thr, 8 waves: wj=wid&1 64-j, hg=wid>>1 64-h; wave tile 4j x 4h,
// acc 64 VGPR, 2 blocks/CU) with ONE change: B staged via global_load_lds DMA
// (R11-proven conflict-free) instead of register round-trip ds_write_b128 at
// t*32 (16-way bank alias -> R10's entire 4.19M conflict count). A-frag ds_writes
// stay (lane-contiguous 16 B -> free 2-way).
__global__ __launch_bounds__(512) void score_mfma(
    const float* __restrict__ X,  const float* __restrict__ b1,
    const float* __restrict__ W2, const float* __restrict__ b2,
    const float* __restrict__ S,  const float* __restrict__ T,
    const _Float16* __restrict__ Wst, const float* __restrict__ Xt,
    float* __restrict__ Sc) {

  const int blk   = blockIdx.x;
  const int bi    = blk >> 1;       // b*256 + i
  const int jbase = (blk & 1) * 128;
  const int b     = bi >> 8;
  const int i     = bi & 255;
  const int t     = threadIdx.x;
  const int lane  = t & 63;
  const int wid   = t >> 6;         // 0..7
  const int wj    = wid & 1;
  const int hg    = wid >> 1;       // 0..3
  const int q     = lane >> 4;
  const int cc    = lane & 15;

  __shared__ __align__(16) float    xi_s[DD];
  __shared__ float pre_s[HH];
  __shared__ float w2_s[HH];
  __shared__ __align__(16) _Float16 As[2][4096];   // 8 KB per buf
  __shared__ __align__(16) _Float16 Bs[2][8192];   // 16 KB per buf
  __shared__ float sc_s[4][128];

  if (t < 256) {
    xi_s[t]  = X[(size_t)bi * DD + t];
    pre_s[t] = S[(size_t)bi * HH + t] + b1[t];
    w2_s[t]  = W2[t];
  }
  __syncthreads();                    // xi_s needed by A-gen

  const float* __restrict__ Tb = T + (size_t)b * NN * HH;

  // A-gen role: thread t handles (qa = t>>7, jl = t&127).
  const int qa = t >> 7;
  const int jl = t & 127;
  const float* __restrict__ xsrc = Xt + (size_t)b * DD * NN + jbase + jl;
  const int awo = ((jl >> 4) * 4 + qa) * 128 + (jl & 15) * 8;  // halves

  // B DMA staging: wave wid covers 2 KB of the 16 KB kstep chunk (2 instrs).
  const char* __restrict__ WstB = (const char*)Wst;   // kstep ks at byte ks*16384
  const int bsrc = wid * 2048 + lane * 16;            // per-lane global offset
  const int bdst = wid * 2048;                        // wave-uniform LDS offset

  // fragment read offsets (halves): frag(tile,q) at (tile*4+q)*128 + cc*8
  const int bro = hg * 2048 + lane * 8;   // hh advances +512
  const int aro = wj * 2048 + lane * 8;   // jj advances +512

  floatx4 a00 = (floatx4)0.f, a01 = (floatx4)0.f, a02 = (floatx4)0.f, a03 = (floatx4)0.f;
  floatx4 a10 = (floatx4)0.f, a11 = (floatx4)0.f, a12 = (floatx4)0.f, a13 = (floatx4)0.f;
  floatx4 a20 = (floatx4)0.f, a21 = (floatx4)0.f, a22 = (floatx4)0.f, a23 = (floatx4)0.f;
  floatx4 a30 = (floatx4)0.f, a31 = (floatx4)0.f, a32 = (floatx4)0.f, a33 = (floatx4)0.f;

  // prologue: stage kstep 0 into buffer 0
  {
    ld_lds16(WstB + bsrc,        (char*)&Bs[0][0] + bdst);
    ld_lds16(WstB + bsrc + 1024, (char*)&Bs[0][0] + bdst + 1024);
    const float xj0 = xsrc[(size_t)(qa * 4 + 0) * NN];
    const float xj1 = xsrc[(size_t)(qa * 4 + 1) * NN];
    const float xj2 = xsrc[(size_t)(qa * 4 + 2) * NN];
    const float xj3 = xsrc[(size_t)(qa * 4 + 3) * NN];
    *(half8*)&As[0][awo] = make_afrag(xi_s[qa * 4 + 0], xi_s[qa * 4 + 1],
                                      xi_s[qa * 4 + 2], xi_s[qa * 4 + 3],
                                      xj0, xj1, xj2, xj3);
  }
  __syncthreads();

  for (int ks = 0; ks < 16; ++ks) {
    const int cur = ks & 1;
    const int nxt = cur ^ 1;
    float nx0, nx1, nx2, nx3;
    if (ks < 15) {
      const char* gB = WstB + (size_t)(ks + 1) * 16384;
      ld_lds16(gB + bsrc,        (char*)&Bs[nxt][0] + bdst);
      ld_lds16(gB + bsrc + 1024, (char*)&Bs[nxt][0] + bdst + 1024);
      const float* __restrict__ xs2 = xsrc + (size_t)((ks + 1) * 16 + qa * 4) * NN;
      nx0 = xs2[0]; nx1 = xs2[NN]; nx2 = xs2[2 * NN]; nx3 = xs2[3 * NN];
    }

    // ---- compute kstep ks from buffer cur ----
    {
      const _Float16* __restrict__ ap = &As[cur][0];
      const _Float16* __restrict__ bp = &Bs[cur][0];
      const half8 bf0 = *(const half8*)&bp[bro];
      const half8 bf1 = *(const half8*)&bp[bro + 512];
      const half8 bf2 = *(const half8*)&bp[bro + 1024];
      const half8 bf3 = *(const half8*)&bp[bro + 1536];
      {
        const half8 af = *(const half8*)&ap[aro];
        MFMA16(af, bf0, a00); MFMA16(af, bf1, a01); MFMA16(af, bf2, a02); MFMA16(af, bf3, a03);
      }
      {
        const half8 af = *(const half8*)&ap[aro + 512];
        MFMA16(af, bf0, a10); MFMA16(af, bf1, a11); MFMA16(af, bf2, a12); MFMA16(af, bf3, a13);
      }
      {
        const half8 af = *(const half8*)&ap[aro + 1024];
        MFMA16(af, bf0, a20); MFMA16(af, bf1, a21); MFMA16(af, bf2, a22); MFMA16(af, bf3, a23);
      }
      {
        const half8 af = *(const half8*)&ap[aro + 1536];
        MFMA16(af, bf0, a30); MFMA16(af, bf1, a31); MFMA16(af, bf2, a32); MFMA16(af, bf3, a33);
      }
    }

    if (ks < 15) {
      const int d0 = (ks + 1) * 16 + qa * 4;
      *(half8*)&As[nxt][awo] = make_afrag(xi_s[d0], xi_s[d0 + 1], xi_s[d0 + 2], xi_s[d0 + 3],
                                          nx0, nx1, nx2, nx3);
    }
    __syncthreads();
  }

  // ---- epilogue: + S_i + T_j + b1, silu, dot w2 ----
  float p00 = 0.f, p01 = 0.f, p02 = 0.f, p03 = 0.f;
  float p10 = 0.f, p11 = 0.f, p12 = 0.f, p13 = 0.f;
  float p20 = 0.f, p21 = 0.f, p22 = 0.f, p23 = 0.f;
  float p30 = 0.f, p31 = 0.f, p32 = 0.f, p33 = 0.f;

#define EPI_ONE(A, jj, r, P) { \
    const float tv = Tb[(size_t)(jbase + wj * 64 + jj * 16 + q * 4 + r) * HH + h]; \
    const float hv = A[r] + pv + tv; \
    const float sv = hv * __frcp_rn(1.f + __expf(-hv)); \
    P = fmaf(sv, w2v, P); }

#define EPI_HH(hh, A0, A1, A2, A3) { \
    const int h = hg * 64 + hh * 16 + cc; \
    const float w2v = w2_s[h]; \
    const float pv  = pre_s[h]; \
    EPI_ONE(A0, 0, 0, p00) EPI_ONE(A0, 0, 1, p01) EPI_ONE(A0, 0, 2, p02) EPI_ONE(A0, 0, 3, p03) \
    EPI_ONE(A1, 1, 0, p10) EPI_ONE(A1, 1, 1, p11) EPI_ONE(A1, 1, 2, p12) EPI_ONE(A1, 1, 3, p13) \
    EPI_ONE(A2, 2, 0, p20) EPI_ONE(A2, 2, 1, p21) EPI_ONE(A2, 2, 2, p22) EPI_ONE(A2, 2, 3, p23) \
    EPI_ONE(A3, 3, 0, p30) EPI_ONE(A3, 3, 1, p31) EPI_ONE(A3, 3, 2, p32) EPI_ONE(A3, 3, 3, p33) }

  EPI_HH(0, a00, a10, a20, a30)
  EPI_HH(1, a01, a11, a21, a31)
  EPI_HH(2, a02, a12, a22, a32)
  EPI_HH(3, a03, a13, a23, a33)

#define REDW(P, jj, r) { \
    float v = P; \
    v += __shfl_xor(v, 1); v += __shfl_xor(v, 2); \
    v += __shfl_xor(v, 4); v += __shfl_xor(v, 8); \
    if (cc == 0) sc_s[hg][wj * 64 + jj * 16 + q * 4 + r] = v; }

  REDW(p00, 0, 0) REDW(p01, 0, 1) REDW(p02, 0, 2) REDW(p03, 0, 3)
  REDW(p10, 1, 0) REDW(p11, 1, 1) REDW(p12, 1, 2) REDW(p13, 1, 3)
  REDW(p20, 2, 0) REDW(p21, 2, 1) REDW(p22, 2, 2) REDW(p23, 2, 3)
  REDW(p30, 3, 0) REDW(p31, 3, 1) REDW(p32, 3, 2) REDW(p33, 3, 3)
  __syncthreads();

  if (t < 128) {
    float s = sc_s[0][t] + sc_s[1][t] + sc_s[2][t] + sc_s[3][t] + b2[0];
    const int jg = jbase + t;
    if (jg == i) s = NEGV;
    Sc[(size_t)bi * NN + jg] = s;
  }
}

// ---------------- softmax over j, one block per (b,i) --------------------------
__global__ __launch_bounds__(256) void softmax_kernel(const float* __restrict__ Sc,
                                                      float* __restrict__ out) {
  const int bi = blockIdx.x;
  const int t  = threadIdx.x;
  __shared__ float red[NN];
  const float s = Sc[(size_t)bi * NN + t];
  red[t] = s;
  __syncthreads();
  for (int k = 128; k > 0; k >>= 1) {
    if (t < k) red[t] = fmaxf(red[t], red[t + k]);
    __syncthreads();
  }
  const float m = red[0];
  __syncthreads();
  const float e = __expf(s - m);
  red[t] = e;
  __syncthreads();
  for (int k = 128; k > 0; k >>= 1) {
    if (t < k) red[t] += red[t + k];
    __syncthreads();
  }
  out[(size_t)bi * NN + t] = e / red[0];
}

extern "C" void kernel_launch(void* const* d_in, const int* in_sizes, int n_in,
                              void* d_out, int out_size, void* d_ws, size_t ws_size,
                              hipStream_t stream) {
  const float* X  = (const float*)d_in[0];
  const float* W1 = (const float*)d_in[1];
  const float* b1 = (const float*)d_in[2];
  const float* W2 = (const float*)d_in[3];
  const float* b2 = (const float*)d_in[4];
  float* out = (float*)d_out;

  float*     Sws = (float*)d_ws;                             // 1 MB
  float*     Tws = Sws + (size_t)BB * NN * HH;               // 1 MB
  _Float16*  Wst = (_Float16*)(Tws + (size_t)BB * NN * HH);  // 256 KB
  float*     Xtw = (float*)(Wst + (size_t)16 * HH * 32);     // 1 MB
  float*     Scw = Xtw + (size_t)BB * DD * NN;               // 1 MB

  prep_kernel<<<256, 256, 0, stream>>>(X, W1, Sws, Tws, Wst, Xtw);
  score_mfma<<<BB * NN * 2, 512, 0, stream>>>(X, b1, W2, b2, Sws, Tws, Wst, Xtw, Scw);
  softmax_kernel<<<BB * NN, 256, 0, stream>>>(Scw, out);
}

// Round 13
// 212.605 us; speedup vs baseline: 1.3290x; 1.1307x over previous
//
#include <hip/hip_runtime.h>

#define BB 4
#define NN 256
#define DD 256
#define HH 256
#define NEGV -1.0e9f

typedef _Float16 half8 __attribute__((ext_vector_type(8)));
typedef __fp16   fp16x2 __attribute__((ext_vector_type(2)));
typedef float floatx4 __attribute__((ext_vector_type(4)));

// ---------------- prep: Wc/Wd -> f16 fragment-contiguous; Xtq; S/T ------------
// Wst layout: [ks 0..15][hgrp 0..15][q 0..3][cc 0..15][e 0..7] halves.
// Fragment (ks,hgrp,q) holds B16[k=ks*32+q*8+e][h=hgrp*16+cc]; k=2*d+t
// (t=0: Wc[d][h], t=1: Wd[d][h]).
// Xtq layout: [b][dq 0..63][j 0..255][dd 0..3] fp32 — one float4 = the 4 d's
// (d = dq*4+dd) an A-frag element needs; lane loads are j-contiguous float4s.
__global__ __launch_bounds__(256) void prep_kernel(const float* __restrict__ X,
                                                   const float* __restrict__ W1,
                                                   float* __restrict__ S,
                                                   float* __restrict__ T,
                                                   _Float16* __restrict__ Wst,
                                                   float* __restrict__ Xtq) {
  const int g = blockIdx.x;    // d = 0..255
  const int h = threadIdx.x;   // 0..255

  {
    const float wcv = W1[(size_t)(2 * DD + g) * HH + h];
    const float wdv = W1[(size_t)(3 * DD + g) * HH + h];
    const int ks = g >> 4;
    const int dd = g & 15;
    const int q  = dd >> 2;
    const int e  = (dd & 3) * 2;
    const int hgrp = h >> 4;
    const int ccw  = h & 15;
    _Float16* p = Wst + ((size_t)((ks * 16 + hgrp) * 4 + q) * 16 + ccw) * 8 + e;
    p[0] = (_Float16)wcv;
    p[1] = (_Float16)wdv;
  }

  const int row0 = g * 4;
  __shared__ float xr[4][DD];
#pragma unroll
  for (int r = 0; r < 4; ++r) xr[r][h] = X[(size_t)(row0 + r) * DD + h];
  __syncthreads();

  {
    const int bb = row0 >> 8;
    const int j0 = row0 & 255;
    // Xtq[bb][h>>2][j0+r][h&3]
    float* xt = Xtq + (size_t)bb * 65536 + (size_t)(h >> 2) * 1024
                    + (size_t)j0 * 4 + (h & 3);
    xt[0] = xr[0][h]; xt[4] = xr[1][h]; xt[8] = xr[2][h]; xt[12] = xr[3][h];
  }

  const float* __restrict__ Wa = W1;
  const float* __restrict__ Wb = W1 + (size_t)DD * HH;
  float sa0 = 0.f, sa1 = 0.f, sa2 = 0.f, sa3 = 0.f;
  float sb0 = 0.f, sb1 = 0.f, sb2 = 0.f, sb3 = 0.f;
#pragma unroll 4
  for (int d = 0; d < DD; ++d) {
    const float wa = Wa[(size_t)d * HH + h];
    const float wb = Wb[(size_t)d * HH + h];
    sa0 = fmaf(xr[0][d], wa, sa0);  sb0 = fmaf(xr[0][d], wb, sb0);
    sa1 = fmaf(xr[1][d], wa, sa1);  sb1 = fmaf(xr[1][d], wb, sb1);
    sa2 = fmaf(xr[2][d], wa, sa2);  sb2 = fmaf(xr[2][d], wb, sb2);
    sa3 = fmaf(xr[3][d], wa, sa3);  sb3 = fmaf(xr[3][d], wb, sb3);
  }
  S[(size_t)(row0 + 0) * HH + h] = sa0;  T[(size_t)(row0 + 0) * HH + h] = sb0;
  S[(size_t)(row0 + 1) * HH + h] = sa1;  T[(size_t)(row0 + 1) * HH + h] = sb1;
  S[(size_t)(row0 + 2) * HH + h] = sa2;  T[(size_t)(row0 + 2) * HH + h] = sb2;
  S[(size_t)(row0 + 3) * HH + h] = sa3;  T[(size_t)(row0 + 3) * HH + h] = sb3;
}

__device__ __forceinline__ half8 make_afrag(const float4 xi, const float4 xj) {
  fp16x2 p0 = __builtin_amdgcn_cvt_pkrtz(__builtin_fabsf(xi.x - xj.x), xi.x * xj.x);
  fp16x2 p1 = __builtin_amdgcn_cvt_pkrtz(__builtin_fabsf(xi.y - xj.y), xi.y * xj.y);
  fp16x2 p2 = __builtin_amdgcn_cvt_pkrtz(__builtin_fabsf(xi.z - xj.z), xi.z * xj.z);
  fp16x2 p3 = __builtin_amdgcn_cvt_pkrtz(__builtin_fabsf(xi.w - xj.w), xi.w * xj.w);
  uint4 u;
  u.x = __builtin_bit_cast(unsigned int, p0);
  u.y = __builtin_bit_cast(unsigned int, p1);
  u.z = __builtin_bit_cast(unsigned int, p2);
  u.w = __builtin_bit_cast(unsigned int, p3);
  return __builtin_bit_cast(half8, u);
}

#define MFMA16(af, bf, acc) acc = __builtin_amdgcn_mfma_f32_16x16x32_f16(af, bf, acc, 0, 0, 0)

// ---------------- score: one block per (b,i) x 128-j half ----------------------
// BARRIER-FREE K-loop (the structural fix for the R8-R12 150-215us plateau where
// every kstep drained vmcnt+lgkm at a block barrier):
//  - B frags: global_load_dwordx4 straight from fragment-contiguous Wst
//    (lanes read consecutive 16 B; same-hg waves hit identical L1 lines);
//  - A frags: generated in registers from Xtq (one float4 = the 4 d's needed);
//  - LDS only holds xi/pre/w2/sc (~5 KB) -> no K-loop __syncthreads at all.
// 512 thr = 8 waves (wj=wid&1: 64 j, hg=wid>>1: 64 h), wave tile 4j x 4h.
__global__ __launch_bounds__(512) void score_mfma(
    const float* __restrict__ X,  const float* __restrict__ b1,
    const float* __restrict__ W2, const float* __restrict__ b2,
    const float* __restrict__ S,  const float* __restrict__ T,
    const _Float16* __restrict__ Wst, const float* __restrict__ Xtq,
    float* __restrict__ Sc) {

  const int blk   = blockIdx.x;
  const int bi    = blk >> 1;       // b*256 + i
  const int jbase = (blk & 1) * 128;
  const int b     = bi >> 8;
  const int i     = bi & 255;
  const int t     = threadIdx.x;
  const int lane  = t & 63;
  const int wid   = t >> 6;         // 0..7
  const int wj    = wid & 1;
  const int hg    = wid >> 1;       // 0..3
  const int q     = lane >> 4;
  const int cc    = lane & 15;

  __shared__ __align__(16) float xi_s[DD];
  __shared__ float pre_s[HH];
  __shared__ float w2_s[HH];
  __shared__ float sc_s[4][128];

  if (t < 256) {
    xi_s[t]  = X[(size_t)bi * DD + t];
    pre_s[t] = S[(size_t)bi * HH + t] + b1[t];
    w2_s[t]  = W2[t];
  }
  __syncthreads();                    // the only pre-epilogue barrier

  const float* __restrict__ Tb = T + (size_t)b * NN * HH;

  // A source: Xtq quad index (ks*4+q)*256 + j ; j = jbase + wj*64 + jj*16 + cc
  const float4* __restrict__ xq = (const float4*)Xtq + (size_t)b * 16384;
  const int xj0 = jbase + wj * 64 + cc;            // + jj*16

  // B source: byte addr Wst + ks*16384 + hg*4096 + lane*16 (+1024 per hh)
  const char* __restrict__ bsrc = (const char*)Wst + hg * 4096 + (size_t)lane * 16;

  floatx4 a00 = (floatx4)0.f, a01 = (floatx4)0.f, a02 = (floatx4)0.f, a03 = (floatx4)0.f;
  floatx4 a10 = (floatx4)0.f, a11 = (floatx4)0.f, a12 = (floatx4)0.f, a13 = (floatx4)0.f;
  floatx4 a20 = (floatx4)0.f, a21 = (floatx4)0.f, a22 = (floatx4)0.f, a23 = (floatx4)0.f;
  floatx4 a30 = (floatx4)0.f, a31 = (floatx4)0.f, a32 = (floatx4)0.f, a33 = (floatx4)0.f;

#pragma unroll 2
  for (int ks = 0; ks < 16; ++ks) {
    const float4 xiv = *(const float4*)&xi_s[ks * 16 + q * 4];
    const char* bk = bsrc + ks * 16384;
    const half8 bf0 = *(const half8*)(bk);
    const half8 bf1 = *(const half8*)(bk + 1024);
    const half8 bf2 = *(const half8*)(bk + 2048);
    const half8 bf3 = *(const half8*)(bk + 3072);
    const int xrow = (ks * 4 + q) * 256 + xj0;
    {
      const float4 xj = ((const float4*)xq)[xrow];
      const half8 af = make_afrag(xiv, xj);
      MFMA16(af, bf0, a00); MFMA16(af, bf1, a01); MFMA16(af, bf2, a02); MFMA16(af, bf3, a03);
    }
    {
      const float4 xj = ((const float4*)xq)[xrow + 16];
      const half8 af = make_afrag(xiv, xj);
      MFMA16(af, bf0, a10); MFMA16(af, bf1, a11); MFMA16(af, bf2, a12); MFMA16(af, bf3, a13);
    }
    {
      const float4 xj = ((const float4*)xq)[xrow + 32];
      const half8 af = make_afrag(xiv, xj);
      MFMA16(af, bf0, a20); MFMA16(af, bf1, a21); MFMA16(af, bf2, a22); MFMA16(af, bf3, a23);
    }
    {
      const float4 xj = ((const float4*)xq)[xrow + 48];
      const half8 af = make_afrag(xiv, xj);
      MFMA16(af, bf0, a30); MFMA16(af, bf1, a31); MFMA16(af, bf2, a32); MFMA16(af, bf3, a33);
    }
  }

  // ---- epilogue: + S_i + T_j + b1, silu, dot w2 ----
  float p00 = 0.f, p01 = 0.f, p02 = 0.f, p03 = 0.f;
  float p10 = 0.f, p11 = 0.f, p12 = 0.f, p13 = 0.f;
  float p20 = 0.f, p21 = 0.f, p22 = 0.f, p23 = 0.f;
  float p30 = 0.f, p31 = 0.f, p32 = 0.f, p33 = 0.f;

#define EPI_ONE(A, jj, r, P) { \
    const float tv = Tb[(size_t)(jbase + wj * 64 + jj * 16 + q * 4 + r) * HH + h]; \
    const float hv = A[r] + pv + tv; \
    const float sv = hv * __frcp_rn(1.f + __expf(-hv)); \
    P = fmaf(sv, w2v, P); }

#define EPI_HH(hh, A0, A1, A2, A3) { \
    const int h = hg * 64 + hh * 16 + cc; \
    const float w2v = w2_s[h]; \
    const float pv  = pre_s[h]; \
    EPI_ONE(A0, 0, 0, p00) EPI_ONE(A0, 0, 1, p01) EPI_ONE(A0, 0, 2, p02) EPI_ONE(A0, 0, 3, p03) \
    EPI_ONE(A1, 1, 0, p10) EPI_ONE(A1, 1, 1, p11) EPI_ONE(A1, 1, 2, p12) EPI_ONE(A1, 1, 3, p13) \
    EPI_ONE(A2, 2, 0, p20) EPI_ONE(A2, 2, 1, p21) EPI_ONE(A2, 2, 2, p22) EPI_ONE(A2, 2, 3, p23) \
    EPI_ONE(A3, 3, 0, p30) EPI_ONE(A3, 3, 1, p31) EPI_ONE(A3, 3, 2, p32) EPI_ONE(A3, 3, 3, p33) }

  EPI_HH(0, a00, a10, a20, a30)
  EPI_HH(1, a01, a11, a21, a31)
  EPI_HH(2, a02, a12, a22, a32)
  EPI_HH(3, a03, a13, a23, a33)

#define REDW(P, jj, r) { \
    float v = P; \
    v += __shfl_xor(v, 1); v += __shfl_xor(v, 2); \
    v += __shfl_xor(v, 4); v += __shfl_xor(v, 8); \
    if (cc == 0) sc_s[hg][wj * 64 + jj * 16 + q * 4 + r] = v; }

  REDW(p00, 0, 0) REDW(p01, 0, 1) REDW(p02, 0, 2) REDW(p03, 0, 3)
  REDW(p10, 1, 0) REDW(p11, 1, 1) REDW(p12, 1, 2) REDW(p13, 1, 3)
  REDW(p20, 2, 0) REDW(p21, 2, 1) REDW(p22, 2, 2) REDW(p23, 2, 3)
  REDW(p30, 3, 0) REDW(p31, 3, 1) REDW(p32, 3, 2) REDW(p33, 3, 3)
  __syncthreads();

  if (t < 128) {
    float s = sc_s[0][t] + sc_s[1][t] + sc_s[2][t] + sc_s[3][t] + b2[0];
    const int jg = jbase + t;
    if (jg == i) s = NEGV;
    Sc[(size_t)bi * NN + jg] = s;
  }
}

// ---------------- softmax over j, one block per (b,i) --------------------------
__global__ __launch_bounds__(256) void softmax_kernel(const float* __restrict__ Sc,
                                                      float* __restrict__ out) {
  const int bi = blockIdx.x;
  const int t  = threadIdx.x;
  __shared__ float red[NN];
  const float s = Sc[(size_t)bi * NN + t];
  red[t] = s;
  __syncthreads();
  for (int k = 128; k > 0; k >>= 1) {
    if (t < k) red[t] = fmaxf(red[t], red[t + k]);
    __syncthreads();
  }
  const float m = red[0];
  __syncthreads();
  const float e = __expf(s - m);
  red[t] = e;
  __syncthreads();
  for (int k = 128; k > 0; k >>= 1) {
    if (t < k) red[t] += red[t + k];
    __syncthreads();
  }
  out[(size_t)bi * NN + t] = e / red[0];
}

extern "C" void kernel_launch(void* const* d_in, const int* in_sizes, int n_in,
                              void* d_out, int out_size, void* d_ws, size_t ws_size,
                              hipStream_t stream) {
  const float* X  = (const float*)d_in[0];
  const float* W1 = (const float*)d_in[1];
  const float* b1 = (const float*)d_in[2];
  const float* W2 = (const float*)d_in[3];
  const float* b2 = (const float*)d_in[4];
  float* out = (float*)d_out;

  float*     Sws = (float*)d_ws;                             // 1 MB
  float*     Tws = Sws + (size_t)BB * NN * HH;               // 1 MB
  _Float16*  Wst = (_Float16*)(Tws + (size_t)BB * NN * HH);  // 256 KB
  float*     Xtq = (float*)(Wst + (size_t)16 * HH * 32);     // 1 MB
  float*     Scw = Xtq + (size_t)BB * DD * NN;               // 1 MB

  prep_kernel<<<256, 256, 0, stream>>>(X, W1, Sws, Tws, Wst, Xtq);
  score_mfma<<<BB * NN * 2, 512, 0, stream>>>(X, b1, W2, b2, Sws, Tws, Wst, Xtq, Scw);
  softmax_kernel<<<BB * NN, 256, 0, stream>>>(Scw, out);
}